// Round 8
// baseline (887.882 us; speedup 1.0000x reference)
//
#include <hip/hip_runtime.h>
#include <math.h>

using u16 = unsigned short;
typedef __attribute__((ext_vector_type(8))) short short8;
typedef __attribute__((ext_vector_type(4))) float f32x4;
typedef __attribute__((ext_vector_type(2))) float f32x2;

// ---------- bf16 helpers ----------
__device__ __forceinline__ float bf2f(u16 u) {
    union { unsigned int i; float f; } c; c.i = ((unsigned int)u) << 16; return c.f;
}
__device__ __forceinline__ u16 f2bf(float f) {
    union { float f; unsigned int i; } c; c.f = f;
    unsigned int x = c.i;
    x += 0x7fffu + ((x >> 16) & 1u);   // round-to-nearest-even
    return (u16)(x >> 16);
}
__device__ __forceinline__ unsigned int pack2bf(float a, float b) {
    return ((unsigned int)f2bf(b) << 16) | (unsigned int)f2bf(a);
}
// tanh-form GELU: x * sigmoid(1.5957691(x + 0.044715 x^3)); max |err| ~3e-4
__device__ __forceinline__ float gelu_f(float x) {
    float z = x * fmaf(x * x, -0.1029431f, -2.3022057f);
    return x / (1.0f + exp2f(z));
}

#define NE 384
#define NTOK 50176      // 2*8*56*56
#define NTW 98
#define NHEAD 12
#define HD 32

// async global->LDS, 16B per lane; LDS dest = wave-uniform base + lane*16
#define GLD(gp, lp) __builtin_amdgcn_global_load_lds( \
    (const __attribute__((address_space(1))) unsigned int*)(gp), \
    (__attribute__((address_space(3))) unsigned int*)(lp), 16, 0, 0)

// ---------------------------------------------------------------------------
// Weight transpose+convert: W fp32 [K][N] -> WT bf16 [N][K]. K,N multiples of 32.
// ---------------------------------------------------------------------------
__global__ __launch_bounds__(256) void k_wt(
    const float* __restrict__ W, u16* __restrict__ WT, int K, int N)
{
    __shared__ float t[32][33];
    int n0 = blockIdx.x * 32, k0 = blockIdx.y * 32;
    int tx = threadIdx.x & 31, ty = threadIdx.x >> 5;   // 8 rows per pass
#pragma unroll
    for (int r = ty; r < 32; r += 8)
        t[r][tx] = W[(size_t)(k0 + r) * N + n0 + tx];
    __syncthreads();
#pragma unroll
    for (int r = ty; r < 32; r += 8)
        WT[(size_t)(n0 + r) * K + k0 + tx] = f2bf(t[tx][r]);
}

// ---------------------------------------------------------------------------
// Precomputed attention bias+mask table, log2e-prescaled, bf16.
// tab[class][head][i][j], i<98, j<128 (j>=98 => -1e30 so exp2 -> 0).
// class bits: 4=bt (wt==3), 2=bh (wh==7), 1=bw (ww==7).
// ---------------------------------------------------------------------------
__global__ __launch_bounds__(256) void k_bias(
    const float* __restrict__ btab, u16* __restrict__ tab)
{
    const int h = blockIdx.x, cls = blockIdx.y;
    const int bt = (cls >> 2) & 1, bh = (cls >> 1) & 1, bw = cls & 1;
    u16* t = tab + ((size_t)cls * NHEAD + h) * 98 * 128;
    for (int e = threadIdx.x; e < 98 * 128; e += 256) {
        int i = e >> 7, j = e & 127;
        float v;
        if (j < 98) {
            int lti = i / 49, lhi = (i % 49) / 7, lwi = i % 7;
            int ltj = j / 49, lhj = (j % 49) / 7, lwj = j % 7;
            int idx = (lti - ltj + 1) * 169 + (lhi - lhj + 6) * 13 + (lwi - lwj + 6);
            v = btab[idx * NHEAD + h];
            int ri = (bt ? (1 + lti) : 0) * 9 + (bh ? (lhi < 4 ? 1 : 2) : 0) * 3
                   + (bw ? (lwi < 4 ? 1 : 2) : 0);
            int rj = (bt ? (1 + ltj) : 0) * 9 + (bh ? (lhj < 4 ? 1 : 2) : 0) * 3
                   + (bw ? (lwj < 4 ? 1 : 2) : 0);
            if (ri != rj) v -= 100.0f;
            v *= 1.4426950408889634f;          // log2(e)
        } else {
            v = -1e30f;
        }
        t[e] = f2bf(v);
    }
}

// ---------------------------------------------------------------------------
// LN1 + cyclic shift (-1,-3,-3) + window partition (chunked). wave/token.
// ---------------------------------------------------------------------------
__global__ __launch_bounds__(256) void k_ln1_win(
    const float* __restrict__ x, const float* __restrict__ g, const float* __restrict__ b,
    u16* __restrict__ xw, int wid_off, int nrows)
{
    int widl = blockIdx.x * 4 + (threadIdx.x >> 6);
    int lane = threadIdx.x & 63;
    if (widl >= nrows) return;
    int wid = wid_off + widl;
    int b_ = wid / NTW, n = wid - b_ * NTW;
    int bi = b_ >> 8, widx = b_ & 255;
    int wt = widx >> 6, wh = (widx >> 3) & 7, ww = widx & 7;
    int lt = n / 49; int rr = n - lt * 49; int lh = rr / 7; int lw = rr - lh * 7;
    int t0 = (wt * 2 + lt + 1) & 7;
    int h0 = wh * 7 + lh + 3; if (h0 >= 56) h0 -= 56;
    int w0 = ww * 7 + lw + 3; if (w0 >= 56) w0 -= 56;
    const float* src = x + (size_t)(((bi * 8 + t0) * 56 + h0) * 56 + w0) * NE;

    float v[6]; float s = 0.f, ss = 0.f;
#pragma unroll
    for (int j = 0; j < 6; j++) {
        v[j] = src[lane + j * 64]; s += v[j]; ss += v[j] * v[j];
    }
#pragma unroll
    for (int off = 32; off; off >>= 1) {
        s += __shfl_xor(s, off, 64); ss += __shfl_xor(ss, off, 64);
    }
    float mean = s * (1.0f / 384.0f);
    float var = ss * (1.0f / 384.0f) - mean * mean;
    float rs = rsqrtf(var + 1e-5f);
    u16* dst = xw + (size_t)widl * NE;
#pragma unroll
    for (int j = 0; j < 6; j++) {
        int e = lane + j * 64;
        dst[e] = f2bf((v[j] - mean) * rs * g[e] + b[e]);
    }
}

// ---------------------------------------------------------------------------
// LN2 on fp32 residual (in d_out), bf16 out, chunked
// ---------------------------------------------------------------------------
__global__ __launch_bounds__(256) void k_ln2(
    const float* __restrict__ xres, const float* __restrict__ g, const float* __restrict__ b,
    u16* __restrict__ o, int nrows)
{
    int wid = blockIdx.x * 4 + (threadIdx.x >> 6);
    int lane = threadIdx.x & 63;
    if (wid >= nrows) return;
    const float* src = xres + (size_t)wid * NE;
    float v[6]; float s = 0.f, ss = 0.f;
#pragma unroll
    for (int j = 0; j < 6; j++) {
        v[j] = src[lane + j * 64]; s += v[j]; ss += v[j] * v[j];
    }
#pragma unroll
    for (int off = 32; off; off >>= 1) {
        s += __shfl_xor(s, off, 64); ss += __shfl_xor(ss, off, 64);
    }
    float mean = s * (1.0f / 384.0f);
    float var = ss * (1.0f / 384.0f) - mean * mean;
    float rs = rsqrtf(var + 1e-5f);
    u16* dst = o + (size_t)wid * NE;
#pragma unroll
    for (int j = 0; j < 6; j++) {
        int e = lane + j * 64;
        dst[e] = f2bf((v[j] - mean) * rs * g[e] + b[e]);
    }
}

// ---------------------------------------------------------------------------
// GEMM: C[M,N] = A[M,K](bf16, lda) @ BT[N,K](bf16, pre-transposed) + bias(fp32).
// 256x128x32 tiles, 4 waves, wave tile 64x128 (32 MFMA / 12 ds_read per
// barrier phase -- 2x MFMA per phase vs 128x128 to cover the LDS read burst).
// T4: 3-buffer LDS rotation (72 KB), 2-deep prefetch, counted vmcnt(6).
// T1: bijective XCD-chunked block swizzle.
// B-staging rows PERMUTED so fragment (nt,lm) -> global col 8*lm+nt:
// each lane owns 8 CONTIGUOUS cols -> single 16B store per row (bf16).
// MODE 0: bf16 out. MODE 1: window-reverse scatter + x shortcut -> fp32 d_out.
// MODE 2: tanh GELU, bf16 out. MODE 3: in-place fp32 residual add (d_out).
// ---------------------------------------------------------------------------
template <int MODE>
__global__ __launch_bounds__(256) void k_gemm(
    const u16* __restrict__ A, int lda, const u16* __restrict__ BT,
    const float* __restrict__ bias, void* __restrict__ Cv,
    const float* __restrict__ extra, int M, int N, int K, int row_off)
{
    __shared__ __align__(16) u16 As[3][256][32];
    __shared__ __align__(16) u16 Bs[3][128][32];

    // ---- XCD-chunked bijective swizzle (m204)
    const int nx = gridDim.x;
    const int nwg = nx * gridDim.y;
    const int L = blockIdx.y * nx + blockIdx.x;
    const int xcd = L & 7, pos = L >> 3;
    const int q = nwg >> 3, r = nwg & 7;
    const int wg = (xcd < r) ? xcd * (q + 1) + pos
                             : r * (q + 1) + (xcd - r) * q + pos;
    const int bn = wg % nx, bm = wg / nx;

    const int tid = threadIdx.x;
    const int lane = tid & 63, wv = tid >> 6;
    const int lm = lane & 15, lg = lane >> 4;

    f32x4 acc[4][8];
#pragma unroll
    for (int a = 0; a < 4; a++)
#pragma unroll
        for (int b = 0; b < 8; b++) acc[a][b] = (f32x4){0.f, 0.f, 0.f, 0.f};

    // ---- hoisted per-lane staging pointers (advance 32 u16 = 64 B / stage)
    const u16 *gA0, *gA1, *gA2, *gA3, *gB0, *gB1;
    {
        int c0 = (wv << 8) + lane;
#define AINIT(P, G) { int c = c0 + ((G) << 6); int rl = c >> 2;               \
        int ra = bm * 256 + rl; if (ra >= M) ra = M - 1;                      \
        P = A + (size_t)ra * lda + ((c & 3) << 3); }
        AINIT(gA0, 0) AINIT(gA1, 1) AINIT(gA2, 2) AINIT(gA3, 3)
#undef AINIT
        int d0 = (wv << 7) + lane;
#define BINIT(P, G) { int c = d0 + ((G) << 6); int rl = c >> 2;               \
        int pb = ((rl & 15) << 3) + (rl >> 4);                                \
        P = BT + (size_t)(bn * 128 + pb) * K + ((c & 3) << 3); }
        BINIT(gB0, 0) BINIT(gB1, 1)
#undef BINIT
    }

    auto stage = [&](int bf) {
        u16* AsB = &As[bf][0][0];
        u16* BsB = &Bs[bf][0][0];
        GLD(gA0, AsB + (((wv << 2) + 0) << 9));
        GLD(gA1, AsB + (((wv << 2) + 1) << 9));
        GLD(gA2, AsB + (((wv << 2) + 2) << 9));
        GLD(gA3, AsB + (((wv << 2) + 3) << 9));
        GLD(gB0, BsB + (((wv << 1) + 0) << 9));
        GLD(gB1, BsB + (((wv << 1) + 1) << 9));
        gA0 += 32; gA1 += 32; gA2 += 32; gA3 += 32; gB0 += 32; gB1 += 32;
    };

    const int niter = K >> 5;           // 12 or 48 -- divisible by 3
    stage(0);
    stage(1);
    const int wr = wv << 6;             // wave row offset (64 rows/wave)

#define GSTEP(I, CUR, PRE)                                                    \
    {                                                                         \
        if ((I) < niter - 1) asm volatile("s_waitcnt vmcnt(6)" ::: "memory"); \
        else                 asm volatile("s_waitcnt vmcnt(0)" ::: "memory"); \
        __builtin_amdgcn_s_barrier();                                         \
        if ((I) + 2 < niter) stage(PRE);                                      \
        short8 fa[4], fb[8];                                                  \
        _Pragma("unroll")                                                     \
        for (int mt = 0; mt < 4; mt++)                                        \
            fa[mt] = *(const short8*)&As[CUR][wr + mt * 16 + lm][lg * 8];     \
        _Pragma("unroll")                                                     \
        for (int nt = 0; nt < 8; nt++)                                        \
            fb[nt] = *(const short8*)&Bs[CUR][nt * 16 + lm][lg * 8];          \
        _Pragma("unroll")                                                     \
        for (int mt = 0; mt < 4; mt++)                                        \
            _Pragma("unroll")                                                 \
            for (int nt = 0; nt < 8; nt++)                                    \
                acc[mt][nt] = __builtin_amdgcn_mfma_f32_16x16x32_bf16(        \
                    fa[mt], fb[nt], acc[mt][nt], 0, 0, 0);                    \
    }

    for (int i = 0; i < niter; i += 3) {
        GSTEP(i, 0, 2);
        GSTEP(i + 1, 1, 0);
        GSTEP(i + 2, 2, 1);
    }
#undef GSTEP

    // epilogue: lane owns 8 contiguous cols [col0, col0+8)
    const int col0 = bn * 128 + (lm << 3);
    float bb[8];
#pragma unroll
    for (int j = 0; j < 8; j++) bb[j] = bias[col0 + j];
#pragma unroll
    for (int mt = 0; mt < 4; mt++) {
#pragma unroll
        for (int r = 0; r < 4; r++) {
            int row = bm * 256 + wr + mt * 16 + lg * 4 + r;
            if (row >= M) continue;
            size_t outrow;
            if (MODE == 1) {
                int grow = row + row_off;
                int b_ = grow / NTW, n = grow - b_ * NTW;
                int bi = b_ >> 8, widx = b_ & 255;
                int wt = widx >> 6, wh = (widx >> 3) & 7, ww = widx & 7;
                int lt = n / 49; int rr2 = n - lt * 49; int lh = rr2 / 7; int lw = rr2 - lh * 7;
                int t0 = (wt * 2 + lt + 1) & 7;
                int h0 = wh * 7 + lh + 3; if (h0 >= 56) h0 -= 56;
                int w0 = ww * 7 + lw + 3; if (w0 >= 56) w0 -= 56;
                outrow = (size_t)(((bi * 8 + t0) * 56 + h0) * 56 + w0);
            } else {
                outrow = (size_t)row;
            }
            float v[8];
#pragma unroll
            for (int nt = 0; nt < 8; nt++) v[nt] = acc[mt][nt][r] + bb[nt];
            if (MODE == 0) {
                union { short8 s; unsigned int w[4]; } o;
#pragma unroll
                for (int j = 0; j < 4; j++) o.w[j] = pack2bf(v[2 * j], v[2 * j + 1]);
                *(short8*)((u16*)Cv + outrow * N + col0) = o.s;
            } else if (MODE == 2) {
                union { short8 s; unsigned int w[4]; } o;
#pragma unroll
                for (int j = 0; j < 4; j++)
                    o.w[j] = pack2bf(gelu_f(v[2 * j]), gelu_f(v[2 * j + 1]));
                *(short8*)((u16*)Cv + outrow * N + col0) = o.s;
            } else if (MODE == 1) {
                float* p = (float*)Cv + outrow * 384 + col0;
                const float* e = extra + outrow * 384 + col0;
                *(f32x4*)p       = (f32x4){v[0] + e[0], v[1] + e[1], v[2] + e[2], v[3] + e[3]};
                *(f32x4*)(p + 4) = (f32x4){v[4] + e[4], v[5] + e[5], v[6] + e[6], v[7] + e[7]};
            } else {
                float* p = (float*)Cv + outrow * N + col0;
                f32x4 a0 = *(const f32x4*)p, a1 = *(const f32x4*)(p + 4);
                *(f32x4*)p       = (f32x4){v[0] + a0[0], v[1] + a0[1], v[2] + a0[2], v[3] + a0[3]};
                *(f32x4*)(p + 4) = (f32x4){v[4] + a1[0], v[5] + a1[1], v[6] + a1[2], v[7] + a1[3]};
            }
        }
    }
}

// ---------------------------------------------------------------------------
// MFMA attention per (head, window). qkv bf16, precomputed bf16 bias table,
// out bf16. Softmax in base-2 via table (log2e-prescaled), normalization
// deferred to the PV epilogue. V rows permuted so output cols pair up.
// ---------------------------------------------------------------------------
__global__ __launch_bounds__(256) void k_attn(
    const u16* __restrict__ qkv, const u16* __restrict__ tab,
    u16* __restrict__ out, int win_off)
{
    __shared__ __align__(16) u16 Qs[112][40];   // Q rows, k=0..31
    __shared__ __align__(16) u16 Ks[128][40];   // K rows, k=0..31
    __shared__ __align__(16) u16 Vt[32][136];   // V transposed (rows permuted)
    __shared__ __align__(16) u16 Ss[112][136];  // P (unnormalized) bf16

    const int h = blockIdx.x, bl = blockIdx.y;
    const int tid = threadIdx.x;
    const int lane = tid & 63, wv = tid >> 6;
    const int lm = lane & 15, lg = lane >> 4;
    const size_t base = (size_t)bl * NTW * 1152 + (size_t)h * HD;

    const int widx = (bl + win_off) & 255;
    const int cls = (((widx >> 6) == 3) ? 4 : 0)
                  | ((((widx >> 3) & 7) == 7) ? 2 : 0)
                  | (((widx & 7) == 7) ? 1 : 0);
    const u16* tabp = tab + ((size_t)cls * NHEAD + h) * 98 * 128;

    // zero pad regions (keep everything finite; V pad cols must be 0)
    for (int i = tid; i < 14 * 40; i += 256) Qs[98 + i / 40][i % 40] = 0;
    for (int i = tid; i < 30 * 40; i += 256) Ks[98 + i / 40][i % 40] = 0;
    for (int i = tid; i < 32 * 30; i += 256) Vt[i / 30][98 + i % 30] = 0;

    // stage Q, K row-major; V transposed with d-permute: row (d&1)*16+(d>>1)
    for (int idx = tid; idx < 3 * 392; idx += 256) {
        int part = idx / 392; int rem = idx - part * 392;
        int n = rem >> 2, dg = (rem & 3) << 3;
        short8 v = *(const short8*)(qkv + base + (size_t)n * 1152 + part * 384 + dg);
        if (part == 0)      *(short8*)&Qs[n][dg] = v;
        else if (part == 1) *(short8*)&Ks[n][dg] = v;
        else {
#pragma unroll
            for (int j = 0; j < 8; j++) {
                int dd = dg + j;
                Vt[((dd & 1) << 4) + (dd >> 1)][n] = (u16)v[j];
            }
        }
    }
    __syncthreads();

    const float scale2 = 0.25503487f;   // (1/sqrt(32)) * log2(e)

    for (int mt = wv; mt < 7; mt += 4) {
        // ---- QK^T: one 16x128 row-block of S in registers ----
        short8 qf = *(const short8*)&Qs[mt * 16 + lm][lg * 8];
        f32x4 sacc[8];
#pragma unroll
        for (int nt = 0; nt < 8; nt++) {
            short8 kf = *(const short8*)&Ks[nt * 16 + lm][lg * 8];
            sacc[nt] = __builtin_amdgcn_mfma_f32_16x16x32_bf16(
                qf, kf, (f32x4){0.f, 0.f, 0.f, 0.f}, 0, 0, 0);
        }
        // ---- base-2 softmax via table; store unnormalized P; keep 1/sum ----
        float inv[4];
#pragma unroll
        for (int r = 0; r < 4; r++) {
            int row = mt * 16 + lg * 4 + r;
            const u16* tr = tabp + (row < 98 ? row : 97) * 128;
            float y[8];
#pragma unroll
            for (int nt = 0; nt < 8; nt++)
                y[nt] = fmaf(sacc[nt][r], scale2, bf2f(tr[nt * 16 + lm]));
            float m = y[0];
#pragma unroll
            for (int nt = 1; nt < 8; nt++) m = fmaxf(m, y[nt]);
            m = fmaxf(m, __shfl_xor(m, 1, 64));
            m = fmaxf(m, __shfl_xor(m, 2, 64));
            m = fmaxf(m, __shfl_xor(m, 4, 64));
            m = fmaxf(m, __shfl_xor(m, 8, 64));
            float sum = 0.f;
#pragma unroll
            for (int nt = 0; nt < 8; nt++) {
                float e = exp2f(y[nt] - m);
                sum += e;
                Ss[row][nt * 16 + lm] = f2bf(e);
            }
            sum += __shfl_xor(sum, 1, 64);
            sum += __shfl_xor(sum, 2, 64);
            sum += __shfl_xor(sum, 4, 64);
            sum += __shfl_xor(sum, 8, 64);
            inv[r] = 1.0f / sum;
        }
        // ---- PV: (16x128) @ (128x32), V rows permuted for paired cols ----
        f32x4 oacc[2];
        oacc[0] = (f32x4){0.f, 0.f, 0.f, 0.f};
        oacc[1] = (f32x4){0.f, 0.f, 0.f, 0.f};
#pragma unroll
        for (int kt = 0; kt < 4; kt++) {
            short8 af = *(const short8*)&Ss[mt * 16 + lm][kt * 32 + lg * 8];
#pragma unroll
            for (int nt = 0; nt < 2; nt++) {
                short8 vf = *(const short8*)&Vt[nt * 16 + lm][kt * 32 + lg * 8];
                oacc[nt] = __builtin_amdgcn_mfma_f32_16x16x32_bf16(
                    af, vf, oacc[nt], 0, 0, 0);
            }
        }
#pragma unroll
        for (int r = 0; r < 4; r++) {
            int row = mt * 16 + lg * 4 + r;
            if (row < 98) {
                float iv = inv[r];
                *(unsigned int*)(out + ((size_t)bl * NTW + row) * NE + h * HD + (lm << 1))
                    = pack2bf(oacc[0][r] * iv, oacc[1][r] * iv);
            }
        }
    }
}

// ---------------------------------------------------------------------------
extern "C" void kernel_launch(void* const* d_in, const int* in_sizes, int n_in,
                              void* d_out, int out_size, void* d_ws, size_t ws_size,
                              hipStream_t stream)
{
    const float* x      = (const float*)d_in[0];
    const float* g1     = (const float*)d_in[1];
    const float* b1     = (const float*)d_in[2];
    const float* qkv_w  = (const float*)d_in[3];
    const float* qkv_b  = (const float*)d_in[4];
    const float* btab   = (const float*)d_in[5];
    const float* proj_w = (const float*)d_in[6];
    const float* proj_b = (const float*)d_in[7];
    const float* g2     = (const float*)d_in[8];
    const float* b2     = (const float*)d_in[9];
    const float* fc1_w  = (const float*)d_in[10];
    const float* fc1_b  = (const float*)d_in[11];
    const float* fc2_w  = (const float*)d_in[12];
    const float* fc2_b  = (const float*)d_in[13];
    float* out = (float*)d_out;          // fp32 output (reference dtype)
    char* ws = (char*)d_ws;

    // ---- bf16 transposed weights + bias table at workspace start ----
    u16* qkv_wt  = (u16*)ws;                 // [1152][384]
    u16* proj_wt = qkv_wt + 442368;          // [384][384]
    u16* fc1_wt  = proj_wt + 147456;         // [1536][384]
    u16* fc2_wt  = fc1_wt + 589824;          // [384][1536]
    u16* att_tab = fc2_wt + 589824;          // [8][12][98][128]
    const size_t wbytes = 3538944 + 2408448;
    char* wsc = ws + wbytes;
    const size_t ws_avail = ws_size - wbytes;

    k_wt<<<dim3(1152 / 32, 384 / 32), 256, 0, stream>>>(qkv_w, qkv_wt, 384, 1152);
    k_wt<<<dim3(384 / 32, 384 / 32), 256, 0, stream>>>(proj_w, proj_wt, 384, 384);
    k_wt<<<dim3(1536 / 32, 384 / 32), 256, 0, stream>>>(fc1_w, fc1_wt, 384, 1536);
    k_wt<<<dim3(384 / 32, 1536 / 32), 256, 0, stream>>>(fc2_w, fc2_wt, 1536, 384);
    k_bias<<<dim3(NHEAD, 8), 256, 0, stream>>>(btab, att_tab);

    // per-window bf16 internal footprint (bytes), phases overlaid:
    //   A: xw 75264 + qkv 225792 + attn 75264 = 376320
    //   B: ln2 75264 + hbuf 301056            = 376320
    const size_t per_w = 376320;
    int wpc = 512;
    while (wpc > 1 && (size_t)wpc * per_w > ws_avail) wpc >>= 1;

    const int nchunk = 512 / wpc;
    const int rows = wpc * NTW;
    const int mtiles = (rows + 255) / 256;

    u16* xw_c   = (u16*)(wsc);
    u16* qkv_c  = (u16*)(wsc + (size_t)wpc * 75264);
    u16* attn_c = (u16*)(wsc + (size_t)wpc * 301056);
    u16* ln2_c  = (u16*)(wsc);
    u16* hbuf_c = (u16*)(wsc + (size_t)wpc * 75264);

    // phase A: LN1+shift+window -> qkv -> attn -> proj scatter(+shortcut, fp32)
    for (int c = 0; c < nchunk; c++) {
        int row0 = c * rows;
        k_ln1_win<<<(rows + 3) / 4, 256, 0, stream>>>(x, g1, b1, xw_c, row0, rows);
        k_gemm<0><<<dim3(9, mtiles), 256, 0, stream>>>(
            xw_c, 384, qkv_wt, qkv_b, qkv_c, nullptr, rows, 1152, 384, 0);
        k_attn<<<dim3(NHEAD, wpc), 256, 0, stream>>>(qkv_c, att_tab, attn_c, c * wpc);
        k_gemm<1><<<dim3(3, mtiles), 256, 0, stream>>>(
            attn_c, 384, proj_wt, proj_b, out, x, rows, 384, 384, row0);
    }

    // phase B: LN2 -> fc1+GELU -> fc2 (+in-place fp32 residual)
    for (int c = 0; c < nchunk; c++) {
        int row0 = c * rows;
        k_ln2<<<(rows + 3) / 4, 256, 0, stream>>>(out + (size_t)row0 * NE, g2, b2, ln2_c, rows);
        k_gemm<2><<<dim3(12, mtiles), 256, 0, stream>>>(
            ln2_c, 384, fc1_wt, fc1_b, hbuf_c, nullptr, rows, 1536, 384, 0);
        k_gemm<3><<<dim3(3, mtiles), 256, 0, stream>>>(
            hbuf_c, 1536, fc2_wt, fc2_b, out + (size_t)row0 * NE, nullptr, rows, 384, 1536, 0);
    }
}

// Round 10
// 651.258 us; speedup vs baseline: 1.3633x; 1.3633x over previous
//
#include <hip/hip_runtime.h>
#include <math.h>

using u16 = unsigned short;
typedef __attribute__((ext_vector_type(8))) short short8;
typedef __attribute__((ext_vector_type(4))) float f32x4;
typedef __attribute__((ext_vector_type(2))) float f32x2;

// ---------- bf16 helpers ----------
__device__ __forceinline__ float bf2f(u16 u) {
    union { unsigned int i; float f; } c; c.i = ((unsigned int)u) << 16; return c.f;
}
__device__ __forceinline__ u16 f2bf(float f) {
    union { float f; unsigned int i; } c; c.f = f;
    unsigned int x = c.i;
    x += 0x7fffu + ((x >> 16) & 1u);   // round-to-nearest-even
    return (u16)(x >> 16);
}
// packed pair via v_cvt_pk_bf16_f32 (no builtin on gfx950 -- inline asm, RNE).
// low half = a, high half = b.
__device__ __forceinline__ unsigned int pack2bf(float a, float b) {
    unsigned int r;
    asm("v_cvt_pk_bf16_f32 %0, %1, %2" : "=v"(r) : "v"(a), "v"(b));
    return r;
}
// tanh-form GELU via rcp (avoids IEEE div sequence); max |err| ~3e-4
__device__ __forceinline__ float gelu_f(float x) {
    float z = x * fmaf(x * x, -0.1029431f, -2.3022057f);
    return x * __builtin_amdgcn_rcpf(1.0f + exp2f(z));
}

#define NE 384
#define NTOK 50176      // 2*8*56*56
#define NTW 98
#define NHEAD 12
#define HD 32

// async global->LDS, 16B per lane; LDS dest = wave-uniform base + lane*16
#define GLD(gp, lp) __builtin_amdgcn_global_load_lds( \
    (const __attribute__((address_space(1))) unsigned int*)(gp), \
    (__attribute__((address_space(3))) unsigned int*)(lp), 16, 0, 0)

// ---------------------------------------------------------------------------
// Weight transpose+convert: W fp32 [K][N] -> WT bf16 [N][K]. K,N multiples of 32.
// ---------------------------------------------------------------------------
__global__ __launch_bounds__(256) void k_wt(
    const float* __restrict__ W, u16* __restrict__ WT, int K, int N)
{
    __shared__ float t[32][33];
    int n0 = blockIdx.x * 32, k0 = blockIdx.y * 32;
    int tx = threadIdx.x & 31, ty = threadIdx.x >> 5;   // 8 rows per pass
#pragma unroll
    for (int r = ty; r < 32; r += 8)
        t[r][tx] = W[(size_t)(k0 + r) * N + n0 + tx];
    __syncthreads();
#pragma unroll
    for (int r = ty; r < 32; r += 8)
        WT[(size_t)(n0 + r) * K + k0 + tx] = f2bf(t[tx][r]);
}

// ---------------------------------------------------------------------------
// Precomputed attention bias+mask table, log2e-prescaled, bf16.
// tab[class][head][i][j], i<98, j<128 (j>=98 => -1e30 so exp2 -> 0).
// class bits: 4=bt (wt==3), 2=bh (wh==7), 1=bw (ww==7).
// ---------------------------------------------------------------------------
__global__ __launch_bounds__(256) void k_bias(
    const float* __restrict__ btab, u16* __restrict__ tab)
{
    const int h = blockIdx.x, cls = blockIdx.y;
    const int bt = (cls >> 2) & 1, bh = (cls >> 1) & 1, bw = cls & 1;
    u16* t = tab + ((size_t)cls * NHEAD + h) * 98 * 128;
    for (int e = threadIdx.x; e < 98 * 128; e += 256) {
        int i = e >> 7, j = e & 127;
        float v;
        if (j < 98) {
            int lti = i / 49, lhi = (i % 49) / 7, lwi = i % 7;
            int ltj = j / 49, lhj = (j % 49) / 7, lwj = j % 7;
            int idx = (lti - ltj + 1) * 169 + (lhi - lhj + 6) * 13 + (lwi - lwj + 6);
            v = btab[idx * NHEAD + h];
            int ri = (bt ? (1 + lti) : 0) * 9 + (bh ? (lhi < 4 ? 1 : 2) : 0) * 3
                   + (bw ? (lwi < 4 ? 1 : 2) : 0);
            int rj = (bt ? (1 + ltj) : 0) * 9 + (bh ? (lhj < 4 ? 1 : 2) : 0) * 3
                   + (bw ? (lwj < 4 ? 1 : 2) : 0);
            if (ri != rj) v -= 100.0f;
            v *= 1.4426950408889634f;          // log2(e)
        } else {
            v = -1e30f;
        }
        t[e] = f2bf(v);
    }
}

// ---------------------------------------------------------------------------
// LN1 + cyclic shift (-1,-3,-3) + window partition (chunked). wave/token.
// ---------------------------------------------------------------------------
__global__ __launch_bounds__(256) void k_ln1_win(
    const float* __restrict__ x, const float* __restrict__ g, const float* __restrict__ b,
    u16* __restrict__ xw, int wid_off, int nrows)
{
    int widl = blockIdx.x * 4 + (threadIdx.x >> 6);
    int lane = threadIdx.x & 63;
    if (widl >= nrows) return;
    int wid = wid_off + widl;
    int b_ = wid / NTW, n = wid - b_ * NTW;
    int bi = b_ >> 8, widx = b_ & 255;
    int wt = widx >> 6, wh = (widx >> 3) & 7, ww = widx & 7;
    int lt = n / 49; int rr = n - lt * 49; int lh = rr / 7; int lw = rr - lh * 7;
    int t0 = (wt * 2 + lt + 1) & 7;
    int h0 = wh * 7 + lh + 3; if (h0 >= 56) h0 -= 56;
    int w0 = ww * 7 + lw + 3; if (w0 >= 56) w0 -= 56;
    const float* src = x + (size_t)(((bi * 8 + t0) * 56 + h0) * 56 + w0) * NE;

    float v[6]; float s = 0.f, ss = 0.f;
#pragma unroll
    for (int j = 0; j < 6; j++) {
        v[j] = src[lane + j * 64]; s += v[j]; ss += v[j] * v[j];
    }
#pragma unroll
    for (int off = 32; off; off >>= 1) {
        s += __shfl_xor(s, off, 64); ss += __shfl_xor(ss, off, 64);
    }
    float mean = s * (1.0f / 384.0f);
    float var = ss * (1.0f / 384.0f) - mean * mean;
    float rs = rsqrtf(var + 1e-5f);
    u16* dst = xw + (size_t)widl * NE;
#pragma unroll
    for (int j = 0; j < 6; j++) {
        int e = lane + j * 64;
        dst[e] = f2bf((v[j] - mean) * rs * g[e] + b[e]);
    }
}

// ---------------------------------------------------------------------------
// LN2 on fp32 residual (in d_out), bf16 out, chunked
// ---------------------------------------------------------------------------
__global__ __launch_bounds__(256) void k_ln2(
    const float* __restrict__ xres, const float* __restrict__ g, const float* __restrict__ b,
    u16* __restrict__ o, int nrows)
{
    int wid = blockIdx.x * 4 + (threadIdx.x >> 6);
    int lane = threadIdx.x & 63;
    if (wid >= nrows) return;
    const float* src = xres + (size_t)wid * NE;
    float v[6]; float s = 0.f, ss = 0.f;
#pragma unroll
    for (int j = 0; j < 6; j++) {
        v[j] = src[lane + j * 64]; s += v[j]; ss += v[j] * v[j];
    }
#pragma unroll
    for (int off = 32; off; off >>= 1) {
        s += __shfl_xor(s, off, 64); ss += __shfl_xor(ss, off, 64);
    }
    float mean = s * (1.0f / 384.0f);
    float var = ss * (1.0f / 384.0f) - mean * mean;
    float rs = rsqrtf(var + 1e-5f);
    u16* dst = o + (size_t)wid * NE;
#pragma unroll
    for (int j = 0; j < 6; j++) {
        int e = lane + j * 64;
        dst[e] = f2bf((v[j] - mean) * rs * g[e] + b[e]);
    }
}

// ---------------------------------------------------------------------------
// GEMM: C[M,N] = A[M,K](bf16, lda) @ BT[N,K](bf16, pre-transposed) + bias(fp32).
// 128x128x32 tiles, 4 waves, mfma 16x16x32 bf16, N % 128 == 0, K % 96 == 0.
// T4: 3-buffer LDS rotation, 2-deep prefetch, counted vmcnt(4).
// T1: bijective XCD-chunked block swizzle.
// B-staging source rows are PERMUTED (per-lane global addr, LDS stays linear)
// so B-fragments nt={0,1} -> output cols {2lm,2lm+1}, nt={2,3} -> {+32,+33}:
// every lane owns adjacent column pairs -> packed u32/float2 stores.
// MODE 0: bf16 out. MODE 1: window-reverse scatter + x shortcut -> fp32 d_out.
// MODE 2: tanh GELU, bf16 out. MODE 3: in-place fp32 residual add (d_out).
// ---------------------------------------------------------------------------
template <int MODE>
__global__ __launch_bounds__(256) void k_gemm(
    const u16* __restrict__ A, int lda, const u16* __restrict__ BT,
    const float* __restrict__ bias, void* __restrict__ Cv,
    const float* __restrict__ extra, int M, int N, int K, int row_off)
{
    __shared__ __align__(16) u16 As[3][128][32];
    __shared__ __align__(16) u16 Bs[3][128][32];

    // ---- XCD-chunked bijective swizzle (m204)
    const int nx = gridDim.x;
    const int nwg = nx * gridDim.y;
    const int L = blockIdx.y * nx + blockIdx.x;
    const int xcd = L & 7, pos = L >> 3;
    const int q = nwg >> 3, r = nwg & 7;
    const int wg = (xcd < r) ? xcd * (q + 1) + pos
                             : r * (q + 1) + (xcd - r) * q + pos;
    const int bn = wg % nx, bm = wg / nx;

    const int tid = threadIdx.x;
    const int lane = tid & 63, wv = tid >> 6;
    const int wr = (wv >> 1) << 6, wc = (wv & 1) << 6;
    const int lm = lane & 15, lg = lane >> 4;

    f32x4 acc[4][4];
#pragma unroll
    for (int a = 0; a < 4; a++)
#pragma unroll
        for (int b = 0; b < 4; b++) acc[a][b] = (f32x4){0.f, 0.f, 0.f, 0.f};

    // ---- hoisted per-lane staging pointers (advance 32 u16 = 64 B / stage)
    const u16 *gA0, *gA1, *gB0, *gB1;
    {
        const int ch0 = (wv << 7) + lane, ch1 = ch0 + 64;
        const int rowl0 = ch0 >> 2, seg0 = (ch0 & 3) << 3;
        const int rowl1 = ch1 >> 2, seg1 = (ch1 & 3) << 3;
        int ra0 = bm * 128 + rowl0; if (ra0 >= M) ra0 = M - 1;
        int ra1 = bm * 128 + rowl1; if (ra1 >= M) ra1 = M - 1;
        gA0 = A + (size_t)ra0 * lda + seg0;
        gA1 = A + (size_t)ra1 * lda + seg1;
        int q0 = rowl0 & 63, q1 = rowl1 & 63;
        int pb0 = (rowl0 & 64) + ((q0 >> 5) << 5) + ((q0 & 15) << 1) + ((q0 >> 4) & 1);
        int pb1 = (rowl1 & 64) + ((q1 >> 5) << 5) + ((q1 & 15) << 1) + ((q1 >> 4) & 1);
        gB0 = BT + (size_t)(bn * 128 + pb0) * K + seg0;
        gB1 = BT + (size_t)(bn * 128 + pb1) * K + seg1;
    }

    auto stage = [&](int bf) {
        u16* AsB = &As[bf][0][0];
        u16* BsB = &Bs[bf][0][0];
        const int o0 = (wv << 1) << 9, o1 = ((wv << 1) + 1) << 9;
        GLD(gA0, AsB + o0);
        GLD(gB0, BsB + o0);
        GLD(gA1, AsB + o1);
        GLD(gB1, BsB + o1);
        gA0 += 32; gA1 += 32; gB0 += 32; gB1 += 32;
    };

    const int niter = K >> 5;           // 12 or 48 -- divisible by 3
    stage(0);
    stage(1);

#define GSTEP(I, CUR, PRE)                                                    \
    {                                                                         \
        if ((I) < niter - 1) asm volatile("s_waitcnt vmcnt(4)" ::: "memory"); \
        else                 asm volatile("s_waitcnt vmcnt(0)" ::: "memory"); \
        __builtin_amdgcn_s_barrier();                                         \
        if ((I) + 2 < niter) stage(PRE);                                      \
        short8 fa[4], fb[4];                                                  \
        _Pragma("unroll")                                                     \
        for (int mt = 0; mt < 4; mt++)                                        \
            fa[mt] = *(const short8*)&As[CUR][wr + mt * 16 + lm][lg * 8];     \
        _Pragma("unroll")                                                     \
        for (int nt = 0; nt < 4; nt++)                                        \
            fb[nt] = *(const short8*)&Bs[CUR][wc + nt * 16 + lm][lg * 8];     \
        _Pragma("unroll")                                                     \
        for (int mt = 0; mt < 4; mt++)                                        \
            _Pragma("unroll")                                                 \
            for (int nt = 0; nt < 4; nt++)                                    \
                acc[mt][nt] = __builtin_amdgcn_mfma_f32_16x16x32_bf16(        \
                    fa[mt], fb[nt], acc[mt][nt], 0, 0, 0);                    \
    }

    for (int i = 0; i < niter; i += 3) {
        GSTEP(i, 0, 2);
        GSTEP(i + 1, 1, 0);
        GSTEP(i + 2, 2, 1);
    }
#undef GSTEP

    // epilogue: lane owns cols {col0,col0+1,col0+32,col0+33}
    const int col0 = bn * 128 + wc + (lm << 1);
    const float b0 = bias[col0], b1 = bias[col0 + 1];
    const float b2 = bias[col0 + 32], b3 = bias[col0 + 33];
#pragma unroll
    for (int mt = 0; mt < 4; mt++) {
#pragma unroll
        for (int r = 0; r < 4; r++) {
            int row = bm * 128 + wr + mt * 16 + lg * 4 + r;
            if (row >= M) continue;
            size_t outrow;
            if (MODE == 1) {
                int grow = row + row_off;
                int b_ = grow / NTW, n = grow - b_ * NTW;
                int bi = b_ >> 8, widx = b_ & 255;
                int wt = widx >> 6, wh = (widx >> 3) & 7, ww = widx & 7;
                int lt = n / 49; int rr2 = n - lt * 49; int lh = rr2 / 7; int lw = rr2 - lh * 7;
                int t0 = (wt * 2 + lt + 1) & 7;
                int h0 = wh * 7 + lh + 3; if (h0 >= 56) h0 -= 56;
                int w0 = ww * 7 + lw + 3; if (w0 >= 56) w0 -= 56;
                outrow = (size_t)(((bi * 8 + t0) * 56 + h0) * 56 + w0);
            } else {
                outrow = (size_t)row;
            }
            float v0 = acc[mt][0][r] + b0, v1 = acc[mt][1][r] + b1;
            float v2 = acc[mt][2][r] + b2, v3 = acc[mt][3][r] + b3;
            if (MODE == 0) {
                u16* p0 = (u16*)Cv + outrow * N + col0;
                *(unsigned int*)p0        = pack2bf(v0, v1);
                *(unsigned int*)(p0 + 32) = pack2bf(v2, v3);
            } else if (MODE == 2) {
                u16* p0 = (u16*)Cv + outrow * N + col0;
                *(unsigned int*)p0        = pack2bf(gelu_f(v0), gelu_f(v1));
                *(unsigned int*)(p0 + 32) = pack2bf(gelu_f(v2), gelu_f(v3));
            } else if (MODE == 1) {
                float* p0 = (float*)Cv + outrow * 384 + col0;
                const float* e0 = extra + outrow * 384 + col0;
                *(f32x2*)p0        = (f32x2){v0 + e0[0],  v1 + e0[1]};
                *(f32x2*)(p0 + 32) = (f32x2){v2 + e0[32], v3 + e0[33]};
            } else {
                float* p0 = (float*)Cv + outrow * N + col0;
                f32x2 a0 = *(const f32x2*)p0, a1 = *(const f32x2*)(p0 + 32);
                *(f32x2*)p0        = (f32x2){v0 + a0[0], v1 + a0[1]};
                *(f32x2*)(p0 + 32) = (f32x2){v2 + a1[0], v3 + a1[1]};
            }
        }
    }
}

// ---------------------------------------------------------------------------
// MFMA attention per (head, window). qkv bf16, precomputed bf16 bias table,
// out bf16. Softmax in base-2 via table (log2e-prescaled), normalization
// deferred to the PV epilogue. V rows permuted so output cols pair up.
// ---------------------------------------------------------------------------
__global__ __launch_bounds__(256) void k_attn(
    const u16* __restrict__ qkv, const u16* __restrict__ tab,
    u16* __restrict__ out, int win_off)
{
    __shared__ __align__(16) u16 Qs[112][40];   // Q rows, k=0..31
    __shared__ __align__(16) u16 Ks[128][40];   // K rows, k=0..31
    __shared__ __align__(16) u16 Vt[32][136];   // V transposed (rows permuted)
    __shared__ __align__(16) u16 Ss[112][136];  // P (unnormalized) bf16

    const int h = blockIdx.x, bl = blockIdx.y;
    const int tid = threadIdx.x;
    const int lane = tid & 63, wv = tid >> 6;
    const int lm = lane & 15, lg = lane >> 4;
    const size_t base = (size_t)bl * NTW * 1152 + (size_t)h * HD;

    const int widx = (bl + win_off) & 255;
    const int cls = (((widx >> 6) == 3) ? 4 : 0)
                  | ((((widx >> 3) & 7) == 7) ? 2 : 0)
                  | (((widx & 7) == 7) ? 1 : 0);
    const u16* tabp = tab + ((size_t)cls * NHEAD + h) * 98 * 128;

    // zero pad regions (keep everything finite; V pad cols must be 0)
    for (int i = tid; i < 14 * 40; i += 256) Qs[98 + i / 40][i % 40] = 0;
    for (int i = tid; i < 30 * 40; i += 256) Ks[98 + i / 40][i % 40] = 0;
    for (int i = tid; i < 32 * 30; i += 256) Vt[i / 30][98 + i % 30] = 0;

    // stage Q, K row-major; V transposed with d-permute: row (d&1)*16+(d>>1)
    for (int idx = tid; idx < 3 * 392; idx += 256) {
        int part = idx / 392; int rem = idx - part * 392;
        int n = rem >> 2, dg = (rem & 3) << 3;
        short8 v = *(const short8*)(qkv + base + (size_t)n * 1152 + part * 384 + dg);
        if (part == 0)      *(short8*)&Qs[n][dg] = v;
        else if (part == 1) *(short8*)&Ks[n][dg] = v;
        else {
#pragma unroll
            for (int j = 0; j < 8; j++) {
                int dd = dg + j;
                Vt[((dd & 1) << 4) + (dd >> 1)][n] = (u16)v[j];
            }
        }
    }
    __syncthreads();

    const float scale2 = 0.25503487f;   // (1/sqrt(32)) * log2(e)

    for (int mt = wv; mt < 7; mt += 4) {
        // ---- QK^T: one 16x128 row-block of S in registers ----
        short8 qf = *(const short8*)&Qs[mt * 16 + lm][lg * 8];
        f32x4 sacc[8];
#pragma unroll
        for (int nt = 0; nt < 8; nt++) {
            short8 kf = *(const short8*)&Ks[nt * 16 + lm][lg * 8];
            sacc[nt] = __builtin_amdgcn_mfma_f32_16x16x32_bf16(
                qf, kf, (f32x4){0.f, 0.f, 0.f, 0.f}, 0, 0, 0);
        }
        // ---- base-2 softmax via table; store unnormalized P; keep 1/sum ----
        float inv[4];
#pragma unroll
        for (int r = 0; r < 4; r++) {
            int row = mt * 16 + lg * 4 + r;
            const u16* tr = tabp + (row < 98 ? row : 97) * 128;
            float y[8];
#pragma unroll
            for (int nt = 0; nt < 8; nt++)
                y[nt] = fmaf(sacc[nt][r], scale2, bf2f(tr[nt * 16 + lm]));
            float m = y[0];
#pragma unroll
            for (int nt = 1; nt < 8; nt++) m = fmaxf(m, y[nt]);
            m = fmaxf(m, __shfl_xor(m, 1, 64));
            m = fmaxf(m, __shfl_xor(m, 2, 64));
            m = fmaxf(m, __shfl_xor(m, 4, 64));
            m = fmaxf(m, __shfl_xor(m, 8, 64));
            float sum = 0.f;
#pragma unroll
            for (int nt = 0; nt < 8; nt++) {
                float e = exp2f(y[nt] - m);
                sum += e;
                Ss[row][nt * 16 + lm] = f2bf(e);
            }
            sum += __shfl_xor(sum, 1, 64);
            sum += __shfl_xor(sum, 2, 64);
            sum += __shfl_xor(sum, 4, 64);
            sum += __shfl_xor(sum, 8, 64);
            inv[r] = __builtin_amdgcn_rcpf(sum);
        }
        // ---- PV: (16x128) @ (128x32), V rows permuted for paired cols ----
        f32x4 oacc[2];
        oacc[0] = (f32x4){0.f, 0.f, 0.f, 0.f};
        oacc[1] = (f32x4){0.f, 0.f, 0.f, 0.f};
#pragma unroll
        for (int kt = 0; kt < 4; kt++) {
            short8 af = *(const short8*)&Ss[mt * 16 + lm][kt * 32 + lg * 8];
#pragma unroll
            for (int nt = 0; nt < 2; nt++) {
                short8 vf = *(const short8*)&Vt[nt * 16 + lm][kt * 32 + lg * 8];
                oacc[nt] = __builtin_amdgcn_mfma_f32_16x16x32_bf16(
                    af, vf, oacc[nt], 0, 0, 0);
            }
        }
#pragma unroll
        for (int r = 0; r < 4; r++) {
            int row = mt * 16 + lg * 4 + r;
            if (row < 98) {
                float iv = inv[r];
                *(unsigned int*)(out + ((size_t)bl * NTW + row) * NE + h * HD + (lm << 1))
                    = pack2bf(oacc[0][r] * iv, oacc[1][r] * iv);
            }
        }
    }
}

// ---------------------------------------------------------------------------
extern "C" void kernel_launch(void* const* d_in, const int* in_sizes, int n_in,
                              void* d_out, int out_size, void* d_ws, size_t ws_size,
                              hipStream_t stream)
{
    const float* x      = (const float*)d_in[0];
    const float* g1     = (const float*)d_in[1];
    const float* b1     = (const float*)d_in[2];
    const float* qkv_w  = (const float*)d_in[3];
    const float* qkv_b  = (const float*)d_in[4];
    const float* btab   = (const float*)d_in[5];
    const float* proj_w = (const float*)d_in[6];
    const float* proj_b = (const float*)d_in[7];
    const float* g2     = (const float*)d_in[8];
    const float* b2     = (const float*)d_in[9];
    const float* fc1_w  = (const float*)d_in[10];
    const float* fc1_b  = (const float*)d_in[11];
    const float* fc2_w  = (const float*)d_in[12];
    const float* fc2_b  = (const float*)d_in[13];
    float* out = (float*)d_out;          // fp32 output (reference dtype)
    char* ws = (char*)d_ws;

    // ---- bf16 transposed weights + bias table at workspace start ----
    u16* qkv_wt  = (u16*)ws;                 // [1152][384]
    u16* proj_wt = qkv_wt + 442368;          // [384][384]
    u16* fc1_wt  = proj_wt + 147456;         // [1536][384]
    u16* fc2_wt  = fc1_wt + 589824;          // [384][1536]
    u16* att_tab = fc2_wt + 589824;          // [8][12][98][128]
    const size_t wbytes = 3538944 + 2408448;
    char* wsc = ws + wbytes;
    const size_t ws_avail = ws_size - wbytes;

    k_wt<<<dim3(1152 / 32, 384 / 32), 256, 0, stream>>>(qkv_w, qkv_wt, 384, 1152);
    k_wt<<<dim3(384 / 32, 384 / 32), 256, 0, stream>>>(proj_w, proj_wt, 384, 384);
    k_wt<<<dim3(1536 / 32, 384 / 32), 256, 0, stream>>>(fc1_w, fc1_wt, 384, 1536);
    k_wt<<<dim3(384 / 32, 1536 / 32), 256, 0, stream>>>(fc2_w, fc2_wt, 1536, 384);
    k_bias<<<dim3(NHEAD, 8), 256, 0, stream>>>(btab, att_tab);

    // per-window bf16 internal footprint (bytes), phases overlaid:
    //   A: xw 75264 + qkv 225792 + attn 75264 = 376320
    //   B: ln2 75264 + hbuf 301056            = 376320
    const size_t per_w = 376320;
    int wpc = 512;
    while (wpc > 1 && (size_t)wpc * per_w > ws_avail) wpc >>= 1;

    const int nchunk = 512 / wpc;
    const int rows = wpc * NTW;
    const int mtiles = (rows + 127) / 128;

    u16* xw_c   = (u16*)(wsc);
    u16* qkv_c  = (u16*)(wsc + (size_t)wpc * 75264);
    u16* attn_c = (u16*)(wsc + (size_t)wpc * 301056);
    u16* ln2_c  = (u16*)(wsc);
    u16* hbuf_c = (u16*)(wsc + (size_t)wpc * 75264);

    // phase A: LN1+shift+window -> qkv -> attn -> proj scatter(+shortcut, fp32)
    for (int c = 0; c < nchunk; c++) {
        int row0 = c * rows;
        k_ln1_win<<<(rows + 3) / 4, 256, 0, stream>>>(x, g1, b1, xw_c, row0, rows);
        k_gemm<0><<<dim3(9, mtiles), 256, 0, stream>>>(
            xw_c, 384, qkv_wt, qkv_b, qkv_c, nullptr, rows, 1152, 384, 0);
        k_attn<<<dim3(NHEAD, wpc), 256, 0, stream>>>(qkv_c, att_tab, attn_c, c * wpc);
        k_gemm<1><<<dim3(3, mtiles), 256, 0, stream>>>(
            attn_c, 384, proj_wt, proj_b, out, x, rows, 384, 384, row0);
    }

    // phase B: LN2 -> fc1+GELU -> fc2 (+in-place fp32 residual)
    for (int c = 0; c < nchunk; c++) {
        int row0 = c * rows;
        k_ln2<<<(rows + 3) / 4, 256, 0, stream>>>(out + (size_t)row0 * NE, g2, b2, ln2_c, rows);
        k_gemm<2><<<dim3(12, mtiles), 256, 0, stream>>>(
            ln2_c, 384, fc1_wt, fc1_b, hbuf_c, nullptr, rows, 1536, 384, 0);
        k_gemm<3><<<dim3(3, mtiles), 256, 0, stream>>>(
            hbuf_c, 1536, fc2_wt, fc2_b, out + (size_t)row0 * NE, nullptr, rows, 384, 1536, 0);
    }
}